// Round 3
// baseline (59.314 us; speedup 1.0000x reference)
//
#include <hip/hip_runtime.h>
#include <cfloat>

#define KK 5
#define BB 8
#define NN 200
#define DD 512

// ---------------------------------------------------------------------------
// Kernel A: per-batch distances + top-5 (smallest) + z_score; also re-inits
// the min-maps in workspace to +INF (ws is NOT re-poisoned between replays).
// 8 blocks x 512 threads (8 waves). Each wave owns rows n = w, w+8, ...;
// lanes split the 512-dim dot product (coalesced float4 loads), butterfly
// shuffle reduce. d2 = ||z||^2 + sum l*(l - 2z)  (single reduction value).
// ---------------------------------------------------------------------------
__global__ __launch_bounds__(512) void topk_init_kernel(
    const float* __restrict__ z, const float* __restrict__ zlib,
    float* __restrict__ zscore, int* __restrict__ idx_out,
    unsigned* __restrict__ minmaps, int mm_total)
{
    int b    = blockIdx.x;    // 0..7
    int tid  = threadIdx.x;   // 0..511
    int lane = tid & 63;
    int w    = tid >> 6;      // wave 0..7

    // init all min-maps to +inf (0x7F800000)
    for (int i = b * 512 + tid; i < mm_total; i += BB * 512)
        minmaps[i] = 0x7F800000u;

    __shared__ float zs[DD];
    __shared__ float dist[NN];
    zs[tid] = z[b * DD + tid];
    __syncthreads();

    // per-lane slice of z (8 floats), reused for every row
    float4 za = *(const float4*)&zs[lane * 8];
    float4 zb = *(const float4*)&zs[lane * 8 + 4];

    // ||z||^2 (computed redundantly per wave via butterfly)
    float zz = za.x*za.x + za.y*za.y + za.z*za.z + za.w*za.w
             + zb.x*zb.x + zb.y*zb.y + zb.z*zb.z + zb.w*zb.w;
    #pragma unroll
    for (int s = 32; s; s >>= 1) zz += __shfl_xor(zz, s);

    for (int n = w; n < NN; n += 8) {
        const float4* lrow = (const float4*)(zlib + (size_t)n * DD);
        float4 la = lrow[lane * 2];
        float4 lb = lrow[lane * 2 + 1];
        float s = la.x*(la.x - 2.f*za.x) + la.y*(la.y - 2.f*za.y)
                + la.z*(la.z - 2.f*za.z) + la.w*(la.w - 2.f*za.w)
                + lb.x*(lb.x - 2.f*zb.x) + lb.y*(lb.y - 2.f*zb.y)
                + lb.z*(lb.z - 2.f*zb.z) + lb.w*(lb.w - 2.f*zb.w);
        #pragma unroll
        for (int m = 32; m; m >>= 1) s += __shfl_xor(s, m);
        if (lane == 0) dist[n] = sqrtf(fmaxf(zz + s, 0.f));
    }
    __syncthreads();

    // iterative 5-round argmin (value, then lowest index on ties — matches
    // jax.lax.top_k selection set)
    __shared__ float sval[512];
    __shared__ int   sidx[512];
    float sum = 0.f;
    for (int it = 0; it < KK; ++it) {
        sval[tid] = (tid < NN) ? dist[tid] : FLT_MAX;
        sidx[tid] = tid;
        __syncthreads();
        for (int s = 256; s > 0; s >>= 1) {
            if (tid < s) {
                float v2 = sval[tid + s]; int i2 = sidx[tid + s];
                if (v2 < sval[tid] || (v2 == sval[tid] && i2 < sidx[tid])) {
                    sval[tid] = v2; sidx[tid] = i2;
                }
            }
            __syncthreads();
        }
        if (tid == 0) {
            int sel = sidx[0];
            idx_out[b * KK + it] = sel;
            sum += sval[0];
            dist[sel] = FLT_MAX;   // exclude for next round
        }
        __syncthreads();
    }
    if (tid == 0) zscore[b] = sum * (1.f / KK);
}

// ---------------------------------------------------------------------------
// Kernel B: per-(b,k,4 pixels) sum over channels of squared diff (float4
// loads, 1KB/wave/instr), atomicMin into per-scale min-map (float-as-uint is
// order-preserving for non-negative values).
// ---------------------------------------------------------------------------
template <int C, int HW>
__device__ __forceinline__ void smap_body4(
    const float* __restrict__ fmap, const float* __restrict__ lib,
    const int* __restrict__ idx, unsigned* __restrict__ mm, int gid)
{
    constexpr int HW4 = HW / 4;
    if (gid >= BB * KK * HW4) return;
    int p4 = gid % HW4;
    int bk = gid / HW4;
    int k  = bk % KK;
    int b  = bk / KK;
    int id = idx[b * KK + k];

    const float4* f = (const float4*)(fmap + (size_t)b  * C * HW) + p4;
    const float4* l = (const float4*)(lib  + (size_t)id * C * HW) + p4;

    float4 acc = {0.f, 0.f, 0.f, 0.f};
#pragma unroll 16
    for (int c = 0; c < C; ++c) {
        float4 lv = l[c * HW4];
        float4 fv = f[c * HW4];
        float dx = lv.x - fv.x, dy = lv.y - fv.y;
        float dz = lv.z - fv.z, dw = lv.w - fv.w;
        acc.x = fmaf(dx, dx, acc.x);
        acc.y = fmaf(dy, dy, acc.y);
        acc.z = fmaf(dz, dz, acc.z);
        acc.w = fmaf(dw, dw, acc.w);
    }
    unsigned* m = mm + b * HW + 4 * p4;
    atomicMin(m + 0, __float_as_uint(acc.x));
    atomicMin(m + 1, __float_as_uint(acc.y));
    atomicMin(m + 2, __float_as_uint(acc.z));
    atomicMin(m + 3, __float_as_uint(acc.w));
}

__global__ __launch_bounds__(256) void smap_kernel(
    const float* __restrict__ fmap0, const float* __restrict__ fmap1,
    const float* __restrict__ fmap2,
    const float* __restrict__ lib0, const float* __restrict__ lib1,
    const float* __restrict__ lib2,
    const int* __restrict__ idx,
    unsigned* __restrict__ mm0, unsigned* __restrict__ mm1,
    unsigned* __restrict__ mm2,
    int nb0, int nb1)
{
    int blk = blockIdx.x;
    if (blk < nb0) {
        smap_body4<64, 3136>(fmap0, lib0, idx, mm0, blk * 256 + threadIdx.x);
    } else if (blk < nb0 + nb1) {
        smap_body4<128, 784>(fmap1, lib1, idx, mm1, (blk - nb0) * 256 + threadIdx.x);
    } else {
        smap_body4<256, 196>(fmap2, lib2, idx, mm2, (blk - nb0 - nb1) * 256 + threadIdx.x);
    }
}

// ---------------------------------------------------------------------------
// Kernel C: bilinear upsample (half-pixel, edge-clamped == jax.image.resize
// "bilinear" for pure upsampling) of the 3 min-maps to 224x224, summed.
// ---------------------------------------------------------------------------
__device__ __forceinline__ float bil(const unsigned* __restrict__ m, int S,
                                     int oy, int ox)
{
    float scale = (float)S * (1.f / 224.f);
    float sy = fminf(fmaxf((oy + 0.5f) * scale - 0.5f, 0.f), (float)(S - 1));
    float sx = fminf(fmaxf((ox + 0.5f) * scale - 0.5f, 0.f), (float)(S - 1));
    int y0 = (int)sy, x0 = (int)sx;
    float ty = sy - y0, tx = sx - x0;
    int y1 = min(y0 + 1, S - 1), x1 = min(x0 + 1, S - 1);
    float v00 = __uint_as_float(m[y0 * S + x0]);
    float v01 = __uint_as_float(m[y0 * S + x1]);
    float v10 = __uint_as_float(m[y1 * S + x0]);
    float v11 = __uint_as_float(m[y1 * S + x1]);
    float top = v00 + tx * (v01 - v00);
    float bot = v10 + tx * (v11 - v10);
    return top + ty * (bot - top);
}

__global__ __launch_bounds__(256) void upsample_kernel(
    const unsigned* __restrict__ mm0, const unsigned* __restrict__ mm1,
    const unsigned* __restrict__ mm2, float* __restrict__ out)
{
    int gid = blockIdx.x * 256 + threadIdx.x;   // over 8*224*224
    if (gid >= BB * 224 * 224) return;
    int ox = gid % 224;
    int r  = gid / 224;
    int oy = r % 224;
    int b  = r / 224;

    float v = bil(mm0 + b * 3136, 56, oy, ox)
            + bil(mm1 + b * 784,  28, oy, ox)
            + bil(mm2 + b * 196,  14, oy, ox);
    out[BB + gid] = v;   // first 8 floats are z_score
}

// ---------------------------------------------------------------------------
extern "C" void kernel_launch(void* const* d_in, const int* in_sizes, int n_in,
                              void* d_out, int out_size, void* d_ws, size_t ws_size,
                              hipStream_t stream)
{
    const float* z     = (const float*)d_in[0];
    const float* zlib  = (const float*)d_in[1];
    const float* fmap0 = (const float*)d_in[2];
    const float* fmap1 = (const float*)d_in[3];
    const float* fmap2 = (const float*)d_in[4];
    const float* lib0  = (const float*)d_in[5];
    const float* lib1  = (const float*)d_in[6];
    const float* lib2  = (const float*)d_in[7];
    float* out = (float*)d_out;

    char* ws = (char*)d_ws;
    int* idx       = (int*)ws;                       // 40 ints
    unsigned* mm0  = (unsigned*)(ws + 256);          // 8*3136
    unsigned* mm1  = mm0 + BB * 3136;                // 8*784
    unsigned* mm2  = mm1 + BB * 784;                 // 8*196
    const int mm_total = BB * (3136 + 784 + 196);    // 32928

    topk_init_kernel<<<BB, 512, 0, stream>>>(z, zlib, out, idx, mm0, mm_total);

    // float4 blocks: scale0: 8*5*784/256 = 122.5 -> 123; scale1: 8*5*196/256
    // = 30.6 -> 31; scale2: 8*5*49/256 = 7.65 -> 8  => 162 blocks
    smap_kernel<<<162, 256, 0, stream>>>(fmap0, fmap1, fmap2,
                                         lib0, lib1, lib2,
                                         idx, mm0, mm1, mm2, 123, 31);

    upsample_kernel<<<1568, 256, 0, stream>>>(mm0, mm1, mm2, out);
}

// Round 4
// 58.195 us; speedup vs baseline: 1.0192x; 1.0192x over previous
//
#include <hip/hip_runtime.h>
#include <cfloat>

#define KK 5
#define BB 8
#define NN 200
#define DD 512

// ---------------------------------------------------------------------------
// Kernel A: per-batch distances + top-5 (smallest) + z_score.
// Round-0 proven structure: one block per batch, thread-per-row dot products
// (512 independent scalar loads/thread, z cached in LDS), then a 5-round
// block-tree argmin (value, lowest index on ties -- matches jax.lax.top_k
// selection set). No shuffles (dependent ds-routed shuffle chains measured
// as a regression in round 3).
// ---------------------------------------------------------------------------
__global__ __launch_bounds__(256) void topk_kernel(
    const float* __restrict__ z, const float* __restrict__ zlib,
    float* __restrict__ zscore, int* __restrict__ idx_out)
{
    int b   = blockIdx.x;   // 0..7
    int tid = threadIdx.x;  // 0..255

    __shared__ float zs[DD];
    __shared__ float dist[NN];
    zs[tid]       = z[b * DD + tid];
    zs[tid + 256] = z[b * DD + tid + 256];
    __syncthreads();

    for (int n = tid; n < NN; n += 256) {
        const float* lrow = zlib + (size_t)n * DD;
        float zz = 0.f, ll = 0.f, dot = 0.f;
        for (int c = 0; c < DD; ++c) {
            float a = zs[c], l = lrow[c];
            zz  = fmaf(a, a, zz);
            ll  = fmaf(l, l, ll);
            dot = fmaf(a, l, dot);
        }
        float d2 = zz + ll - 2.f * dot;
        dist[n] = sqrtf(fmaxf(d2, 0.f));
    }
    __syncthreads();

    __shared__ float sval[256];
    __shared__ int   sidx[256];
    float sum = 0.f;
    for (int it = 0; it < KK; ++it) {
        sval[tid] = (tid < NN) ? dist[tid] : FLT_MAX;
        sidx[tid] = tid;
        __syncthreads();
        for (int s = 128; s > 0; s >>= 1) {
            if (tid < s) {
                float v2 = sval[tid + s]; int i2 = sidx[tid + s];
                if (v2 < sval[tid] || (v2 == sval[tid] && i2 < sidx[tid])) {
                    sval[tid] = v2; sidx[tid] = i2;
                }
            }
            __syncthreads();
        }
        if (tid == 0) {
            int sel = sidx[0];
            idx_out[b * KK + it] = sel;
            sum += sval[0];
            dist[sel] = FLT_MAX;   // exclude for next round
        }
        __syncthreads();
    }
    if (tid == 0) zscore[b] = sum * (1.f / KK);
}

// ---------------------------------------------------------------------------
// Kernel B: per-(b,k,4 pixels) sum over channels of squared diff (float4
// loads, 1KB/wave/instr). Plain stores into per-(b,k) sum-map slots laid out
// [b][hw][8] (k innermost, padded to 8 floats -> 32B-aligned slots). No
// atomics, no init pass; every slot k<5 fully overwritten each call.
// ---------------------------------------------------------------------------
template <int C, int HW>
__device__ __forceinline__ void smap_body4(
    const float* __restrict__ fmap, const float* __restrict__ lib,
    const int* __restrict__ idx, float* __restrict__ smap, int gid)
{
    constexpr int HW4 = HW / 4;
    if (gid >= BB * KK * HW4) return;
    int p4 = gid % HW4;
    int bk = gid / HW4;
    int k  = bk % KK;
    int b  = bk / KK;
    int id = idx[b * KK + k];

    const float4* f = (const float4*)(fmap + (size_t)b  * C * HW) + p4;
    const float4* l = (const float4*)(lib  + (size_t)id * C * HW) + p4;

    float4 acc = {0.f, 0.f, 0.f, 0.f};
#pragma unroll 16
    for (int c = 0; c < C; ++c) {
        float4 lv = l[c * HW4];
        float4 fv = f[c * HW4];
        float dx = lv.x - fv.x, dy = lv.y - fv.y;
        float dz = lv.z - fv.z, dw = lv.w - fv.w;
        acc.x = fmaf(dx, dx, acc.x);
        acc.y = fmaf(dy, dy, acc.y);
        acc.z = fmaf(dz, dz, acc.z);
        acc.w = fmaf(dw, dw, acc.w);
    }
    float* s = smap + ((size_t)b * HW + 4 * p4) * 8 + k;
    s[0 * 8] = acc.x;
    s[1 * 8] = acc.y;
    s[2 * 8] = acc.z;
    s[3 * 8] = acc.w;
}

__global__ __launch_bounds__(256) void smap_kernel(
    const float* __restrict__ fmap0, const float* __restrict__ fmap1,
    const float* __restrict__ fmap2,
    const float* __restrict__ lib0, const float* __restrict__ lib1,
    const float* __restrict__ lib2,
    const int* __restrict__ idx,
    float* __restrict__ sm0, float* __restrict__ sm1, float* __restrict__ sm2,
    int nb0, int nb1)
{
    int blk = blockIdx.x;
    if (blk < nb0) {
        smap_body4<64, 3136>(fmap0, lib0, idx, sm0, blk * 256 + threadIdx.x);
    } else if (blk < nb0 + nb1) {
        smap_body4<128, 784>(fmap1, lib1, idx, sm1, (blk - nb0) * 256 + threadIdx.x);
    } else {
        smap_body4<256, 196>(fmap2, lib2, idx, sm2, (blk - nb0 - nb1) * 256 + threadIdx.x);
    }
}

// ---------------------------------------------------------------------------
// Kernel C: fused min-over-k + bilinear upsample + 3-scale sum.
// min commutes with the per-tap gather, so min_k then bilerp == bilerp of
// min-map. Half-pixel, edge-clamped == jax.image.resize "bilinear" for pure
// upsampling. Taps read float4(k0..3)+float(k4) from 32B-aligned slots.
// ---------------------------------------------------------------------------
__device__ __forceinline__ float tap_min(const float* __restrict__ slot)
{
    float4 v = *(const float4*)slot;
    return fminf(fminf(fminf(v.x, v.y), fminf(v.z, v.w)), slot[4]);
}

template <int S, int HW>
__device__ __forceinline__ float bil5(const float* __restrict__ sm, int b,
                                      int oy, int ox)
{
    const float scale = (float)S * (1.f / 224.f);
    float sy = fminf(fmaxf((oy + 0.5f) * scale - 0.5f, 0.f), (float)(S - 1));
    float sx = fminf(fmaxf((ox + 0.5f) * scale - 0.5f, 0.f), (float)(S - 1));
    int y0 = (int)sy, x0 = (int)sx;
    float ty = sy - y0, tx = sx - x0;
    int y1 = min(y0 + 1, S - 1), x1 = min(x0 + 1, S - 1);
    const float* base = sm + (size_t)b * HW * 8;
    float v00 = tap_min(base + (y0 * S + x0) * 8);
    float v01 = tap_min(base + (y0 * S + x1) * 8);
    float v10 = tap_min(base + (y1 * S + x0) * 8);
    float v11 = tap_min(base + (y1 * S + x1) * 8);
    float top = v00 + tx * (v01 - v00);
    float bot = v10 + tx * (v11 - v10);
    return top + ty * (bot - top);
}

__global__ __launch_bounds__(256) void upsample_kernel(
    const float* __restrict__ sm0, const float* __restrict__ sm1,
    const float* __restrict__ sm2, float* __restrict__ out)
{
    int gid = blockIdx.x * 256 + threadIdx.x;   // over 8*224*224
    if (gid >= BB * 224 * 224) return;
    int ox = gid % 224;
    int r  = gid / 224;
    int oy = r % 224;
    int b  = r / 224;

    float v = bil5<56, 3136>(sm0, b, oy, ox)
            + bil5<28,  784>(sm1, b, oy, ox)
            + bil5<14,  196>(sm2, b, oy, ox);
    out[BB + gid] = v;   // first 8 floats are z_score
}

// ---------------------------------------------------------------------------
extern "C" void kernel_launch(void* const* d_in, const int* in_sizes, int n_in,
                              void* d_out, int out_size, void* d_ws, size_t ws_size,
                              hipStream_t stream)
{
    const float* z     = (const float*)d_in[0];
    const float* zlib  = (const float*)d_in[1];
    const float* fmap0 = (const float*)d_in[2];
    const float* fmap1 = (const float*)d_in[3];
    const float* fmap2 = (const float*)d_in[4];
    const float* lib0  = (const float*)d_in[5];
    const float* lib1  = (const float*)d_in[6];
    const float* lib2  = (const float*)d_in[7];
    float* out = (float*)d_out;

    char* ws = (char*)d_ws;
    int*   idx = (int*)ws;                         // 40 ints
    float* sm0 = (float*)(ws + 256);               // 8*3136*8 floats
    float* sm1 = sm0 + (size_t)BB * 3136 * 8;      // 8*784*8
    float* sm2 = sm1 + (size_t)BB * 784 * 8;       // 8*196*8

    topk_kernel<<<BB, 256, 0, stream>>>(z, zlib, out, idx);

    // float4 blocks: scale0: 8*5*784/256 -> 123; scale1: 8*5*196/256 -> 31;
    // scale2: 8*5*49/256 -> 8  => 162 blocks
    smap_kernel<<<162, 256, 0, stream>>>(fmap0, fmap1, fmap2,
                                         lib0, lib1, lib2,
                                         idx, sm0, sm1, sm2, 123, 31);

    upsample_kernel<<<1568, 256, 0, stream>>>(sm0, sm1, sm2, out);
}

// Round 5
// 52.637 us; speedup vs baseline: 1.1269x; 1.1056x over previous
//
#include <hip/hip_runtime.h>
#include <cfloat>

#define KK 5
#define BB 8
#define NN 200
#define DD 512

// ---------------------------------------------------------------------------
// Kernel A: per-batch distances + top-5 (smallest) + z_score.
// One block per batch, thread-per-row dot products with FLOAT4 row loads
// (128 load instrs/thread instead of 512 -> 4x less exposed latency), z
// staged in LDS as float4 (same-address broadcast across lanes is free).
// Then 5-round block-tree argmin (value, lowest index on ties -- matches
// jax.lax.top_k selection set).
// ---------------------------------------------------------------------------
__global__ __launch_bounds__(256) void topk_kernel(
    const float* __restrict__ z, const float* __restrict__ zlib,
    float* __restrict__ zscore, int* __restrict__ idx_out)
{
    int b   = blockIdx.x;   // 0..7
    int tid = threadIdx.x;  // 0..255

    __shared__ float4 zs4[DD / 4];   // 128 float4
    __shared__ float  dist[NN];
    if (tid < DD / 4)
        zs4[tid] = ((const float4*)(z + b * DD))[tid];
    __syncthreads();

    for (int n = tid; n < NN; n += 256) {
        const float4* lrow = (const float4*)(zlib + (size_t)n * DD);
        float zz = 0.f, ll = 0.f, dot = 0.f;
#pragma unroll 8
        for (int c = 0; c < DD / 4; ++c) {
            float4 a = zs4[c];
            float4 l = lrow[c];
            zz  = fmaf(a.x, a.x, fmaf(a.y, a.y, fmaf(a.z, a.z, fmaf(a.w, a.w, zz))));
            ll  = fmaf(l.x, l.x, fmaf(l.y, l.y, fmaf(l.z, l.z, fmaf(l.w, l.w, ll))));
            dot = fmaf(a.x, l.x, fmaf(a.y, l.y, fmaf(a.z, l.z, fmaf(a.w, l.w, dot))));
        }
        float d2 = zz + ll - 2.f * dot;
        dist[n] = sqrtf(fmaxf(d2, 0.f));
    }
    __syncthreads();

    __shared__ float sval[256];
    __shared__ int   sidx[256];
    float sum = 0.f;
    for (int it = 0; it < KK; ++it) {
        sval[tid] = (tid < NN) ? dist[tid] : FLT_MAX;
        sidx[tid] = tid;
        __syncthreads();
        for (int s = 128; s > 0; s >>= 1) {
            if (tid < s) {
                float v2 = sval[tid + s]; int i2 = sidx[tid + s];
                if (v2 < sval[tid] || (v2 == sval[tid] && i2 < sidx[tid])) {
                    sval[tid] = v2; sidx[tid] = i2;
                }
            }
            __syncthreads();
        }
        if (tid == 0) {
            int sel = sidx[0];
            idx_out[b * KK + it] = sel;
            sum += sval[0];
            dist[sel] = FLT_MAX;   // exclude for next round
        }
        __syncthreads();
    }
    if (tid == 0) zscore[b] = sum * (1.f / KK);
}

// ---------------------------------------------------------------------------
// Kernel B: thread per (k,b,pixel); sum over channels of squared diff.
// 644 blocks / 2576 waves -> all 256 CUs engaged (round-4's float4 variant
// left ~94 CUs idle at 162 blocks). Scalar loads are perfectly coalesced
// (consecutive lanes -> consecutive pixels). Plain coalesced stores into
// per-k planes sm[k][b][hw]; every element overwritten each call ->
// deterministic, no atomics, no init pass.
// ---------------------------------------------------------------------------
template <int C, int HW>
__device__ __forceinline__ void smap_body(
    const float* __restrict__ fmap, const float* __restrict__ lib,
    const int* __restrict__ idx, float* __restrict__ sm, int gid)
{
    if (gid >= KK * BB * HW) return;
    int px = gid % HW;
    int r  = gid / HW;
    int b  = r % BB;
    int k  = r / BB;
    int id = idx[b * KK + k];

    const float* f = fmap + (size_t)b  * C * HW + px;
    const float* l = lib  + (size_t)id * C * HW + px;

    float acc = 0.f;
#pragma unroll 16
    for (int c = 0; c < C; ++c) {
        float d = l[(size_t)c * HW] - f[(size_t)c * HW];
        acc = fmaf(d, d, acc);
    }
    sm[(size_t)(k * BB + b) * HW + px] = acc;
}

__global__ __launch_bounds__(256) void smap_kernel(
    const float* __restrict__ fmap0, const float* __restrict__ fmap1,
    const float* __restrict__ fmap2,
    const float* __restrict__ lib0, const float* __restrict__ lib1,
    const float* __restrict__ lib2,
    const int* __restrict__ idx,
    float* __restrict__ sm0, float* __restrict__ sm1, float* __restrict__ sm2,
    int nb0, int nb1)
{
    int blk = blockIdx.x;
    if (blk < nb0) {
        smap_body<64, 3136>(fmap0, lib0, idx, sm0, blk * 256 + threadIdx.x);
    } else if (blk < nb0 + nb1) {
        smap_body<128, 784>(fmap1, lib1, idx, sm1, (blk - nb0) * 256 + threadIdx.x);
    } else {
        smap_body<256, 196>(fmap2, lib2, idx, sm2, (blk - nb0 - nb1) * 256 + threadIdx.x);
    }
}

// ---------------------------------------------------------------------------
// Kernel C: fused min-over-k + bilinear upsample + 3-scale sum.
// min commutes with the per-tap gather. Half-pixel, edge-clamped ==
// jax.image.resize "bilinear" for pure upsampling. Taps read the 5 k-planes
// (sm buffers total ~0.8 MB -> L1/L2 resident).
// ---------------------------------------------------------------------------
template <int S, int HW>
__device__ __forceinline__ float tap_min(const float* __restrict__ sm, int b,
                                         int yx)
{
    float m = FLT_MAX;
#pragma unroll
    for (int k = 0; k < KK; ++k)
        m = fminf(m, sm[(size_t)(k * BB + b) * HW + yx]);
    return m;
}

template <int S, int HW>
__device__ __forceinline__ float bil5(const float* __restrict__ sm, int b,
                                      int oy, int ox)
{
    const float scale = (float)S * (1.f / 224.f);
    float sy = fminf(fmaxf((oy + 0.5f) * scale - 0.5f, 0.f), (float)(S - 1));
    float sx = fminf(fmaxf((ox + 0.5f) * scale - 0.5f, 0.f), (float)(S - 1));
    int y0 = (int)sy, x0 = (int)sx;
    float ty = sy - y0, tx = sx - x0;
    int y1 = min(y0 + 1, S - 1), x1 = min(x0 + 1, S - 1);
    float v00 = tap_min<S, HW>(sm, b, y0 * S + x0);
    float v01 = tap_min<S, HW>(sm, b, y0 * S + x1);
    float v10 = tap_min<S, HW>(sm, b, y1 * S + x0);
    float v11 = tap_min<S, HW>(sm, b, y1 * S + x1);
    float top = v00 + tx * (v01 - v00);
    float bot = v10 + tx * (v11 - v10);
    return top + ty * (bot - top);
}

__global__ __launch_bounds__(256) void upsample_kernel(
    const float* __restrict__ sm0, const float* __restrict__ sm1,
    const float* __restrict__ sm2, float* __restrict__ out)
{
    int gid = blockIdx.x * 256 + threadIdx.x;   // over 8*224*224
    if (gid >= BB * 224 * 224) return;
    int ox = gid % 224;
    int r  = gid / 224;
    int oy = r % 224;
    int b  = r / 224;

    float v = bil5<56, 3136>(sm0, b, oy, ox)
            + bil5<28,  784>(sm1, b, oy, ox)
            + bil5<14,  196>(sm2, b, oy, ox);
    out[BB + gid] = v;   // first 8 floats are z_score
}

// ---------------------------------------------------------------------------
extern "C" void kernel_launch(void* const* d_in, const int* in_sizes, int n_in,
                              void* d_out, int out_size, void* d_ws, size_t ws_size,
                              hipStream_t stream)
{
    const float* z     = (const float*)d_in[0];
    const float* zlib  = (const float*)d_in[1];
    const float* fmap0 = (const float*)d_in[2];
    const float* fmap1 = (const float*)d_in[3];
    const float* fmap2 = (const float*)d_in[4];
    const float* lib0  = (const float*)d_in[5];
    const float* lib1  = (const float*)d_in[6];
    const float* lib2  = (const float*)d_in[7];
    float* out = (float*)d_out;

    char* ws = (char*)d_ws;
    int*   idx = (int*)ws;                          // 40 ints
    float* sm0 = (float*)(ws + 256);                // 5*8*3136 floats
    float* sm1 = sm0 + (size_t)KK * BB * 3136;      // 5*8*784
    float* sm2 = sm1 + (size_t)KK * BB * 784;       // 5*8*196

    topk_kernel<<<BB, 256, 0, stream>>>(z, zlib, out, idx);

    // blocks: scale0: 5*8*3136/256 = 490; scale1: ceil(31360/256) = 123;
    // scale2: ceil(7840/256) = 31  => 644 blocks
    smap_kernel<<<644, 256, 0, stream>>>(fmap0, fmap1, fmap2,
                                         lib0, lib1, lib2,
                                         idx, sm0, sm1, sm2, 490, 123);

    upsample_kernel<<<1568, 256, 0, stream>>>(sm0, sm1, sm2, out);
}